// Round 7
// baseline (789.481 us; speedup 1.0000x reference)
//
#include <hip/hip_runtime.h>

typedef float v4 __attribute__((ext_vector_type(4)));

__device__ __forceinline__ float leaky(float x) { return x >= 0.f ? x : 0.2f * x; }
__device__ __forceinline__ float elu(float x) { return x > 0.f ? x : expm1f(x); }

#define WAITLDS() do { asm volatile("s_waitcnt lgkmcnt(0)" ::: "memory"); \
                       __builtin_amdgcn_wave_barrier(); } while (0)

// union scratch: gemm1 needs 64*68 + 64*64 = 8448 floats = 33792 B (largest phase)
#define SMEM_FLOATS (64 * 68 + 64 * 64)

// ---- software grid barrier: monotone counter, device-scope ----
__device__ __forceinline__ void gsync(int* bar, int phase, int nblk) {
  __syncthreads();
  if (threadIdx.x == 0) {
    __threadfence();   // release: flush this block's writes device-wide
    __hip_atomic_fetch_add(bar, 1, __ATOMIC_RELEASE, __HIP_MEMORY_SCOPE_AGENT);
    const int target = phase * nblk;
    while (__hip_atomic_load(bar, __ATOMIC_ACQUIRE, __HIP_MEMORY_SCOPE_AGENT) < target)
      __builtin_amdgcn_s_sleep(2);
    __threadfence();   // acquire: invalidate stale L1/L2 lines
  }
  __syncthreads();
}

// ---- GEMM1 tile: h1[n,256] = emb[nidx[n],128] @ W1[128,256] + alpha epilogue ----
__device__ __forceinline__ void gemm1_tile(
    int tile, const int* __restrict__ nidx, const float* __restrict__ emb,
    const float* __restrict__ W1, const float* __restrict__ asv,
    const float* __restrict__ adv, float* __restrict__ h1,
    float* __restrict__ as1, float* __restrict__ ad1, int nN, float* smem) {
  float* xs = smem;             // 64*68
  float* Ws = smem + 64 * 68;   // 64*64
  int t = threadIdx.x;
  int nbase = (tile >> 2) * 64;
  int head  = tile & 3;
  int cbase = head * 64;
  int c0 = (t & 15) * 4;
  int n0 = (t >> 4) * 4;
  float acc[4][4];
  for (int i = 0; i < 4; ++i) for (int j = 0; j < 4; ++j) acc[i][j] = 0.f;
  v4 z = (v4)(0.f);
  for (int kc = 0; kc < 2; ++kc) {
    __syncthreads();
    {
      int sn = t >> 2;
      int node = nbase + sn;
      int kp = (t & 3) * 16;
      bool v = node < nN;
      const float* sp = &emb[(size_t)nidx[v ? node : nN - 1] * 128 + kc * 64 + kp];
      v4 a0 = v ? *(const v4*)(sp + 0)  : z;
      v4 a1 = v ? *(const v4*)(sp + 4)  : z;
      v4 a2 = v ? *(const v4*)(sp + 8)  : z;
      v4 a3 = v ? *(const v4*)(sp + 12) : z;
      *(v4*)&xs[sn * 68 + kp + 0]  = a0;
      *(v4*)&xs[sn * 68 + kp + 4]  = a1;
      *(v4*)&xs[sn * 68 + kp + 8]  = a2;
      *(v4*)&xs[sn * 68 + kp + 12] = a3;
    }
    {
      int kk = t >> 2;
      int cp = (t & 3) * 16;
      const float* wp = &W1[(size_t)(kc * 64 + kk) * 256 + cbase + cp];
      v4 w0 = *(const v4*)(wp + 0);
      v4 w1 = *(const v4*)(wp + 4);
      v4 w2 = *(const v4*)(wp + 8);
      v4 w3 = *(const v4*)(wp + 12);
      *(v4*)&Ws[kk * 64 + cp + 0]  = w0;
      *(v4*)&Ws[kk * 64 + cp + 4]  = w1;
      *(v4*)&Ws[kk * 64 + cp + 8]  = w2;
      *(v4*)&Ws[kk * 64 + cp + 12] = w3;
    }
    __syncthreads();
    #pragma unroll 4
    for (int kk = 0; kk < 64; kk += 4) {
      v4 xv[4], wv[4];
      for (int i = 0; i < 4; ++i) xv[i] = *(const v4*)&xs[(n0 + i) * 68 + kk];
      for (int j = 0; j < 4; ++j) wv[j] = *(const v4*)&Ws[(kk + j) * 64 + c0];
      for (int i = 0; i < 4; ++i)
        for (int j = 0; j < 4; ++j) {
          float xd = xv[i][j];
          acc[i][0] += xd * wv[j][0];
          acc[i][1] += xd * wv[j][1];
          acc[i][2] += xd * wv[j][2];
          acc[i][3] += xd * wv[j][3];
        }
    }
  }
  v4 asl = *(const v4*)&asv[cbase + c0];
  v4 adl = *(const v4*)&adv[cbase + c0];
  for (int i = 0; i < 4; ++i) {
    int node = nbase + n0 + i;
    v4 o; o[0] = acc[i][0]; o[1] = acc[i][1]; o[2] = acc[i][2]; o[3] = acc[i][3];
    float ps = o[0]*asl[0] + o[1]*asl[1] + o[2]*asl[2] + o[3]*asl[3];
    float pd = o[0]*adl[0] + o[1]*adl[1] + o[2]*adl[2] + o[3]*adl[3];
    ps += __shfl_xor(ps, 1); pd += __shfl_xor(pd, 1);
    ps += __shfl_xor(ps, 2); pd += __shfl_xor(pd, 2);
    ps += __shfl_xor(ps, 4); pd += __shfl_xor(pd, 4);
    ps += __shfl_xor(ps, 8); pd += __shfl_xor(pd, 8);
    if (node < nN) {
      *(v4*)&h1[(size_t)node * 256 + cbase + c0] = o;
      if ((t & 15) == 0) {
        as1[(size_t)node * 4 + head] = ps;
        ad1[(size_t)node * 4 + head] = pd;
      }
    }
  }
}

// ---- GEMM2 tile: h2[n,64] = x2[n,256] @ W2[256,64] + alpha epilogue ----
__device__ __forceinline__ void gemm2_tile(
    int tile, const float* __restrict__ x2, const float* __restrict__ W2,
    const float* __restrict__ asv, const float* __restrict__ adv,
    float* __restrict__ h2, float* __restrict__ as2, float* __restrict__ ad2,
    int nN, float* smem) {
  float* xs = smem;             // 32*68
  float* Ws = smem + 32 * 68;   // 64*64
  int t = threadIdx.x;
  int nbase = tile * 32;
  int c0 = (t & 15) * 4;
  int n0 = (t >> 4) * 2;
  float acc[2][4];
  for (int i = 0; i < 2; ++i) for (int j = 0; j < 4; ++j) acc[i][j] = 0.f;
  v4 z = (v4)(0.f);
  for (int kc = 0; kc < 4; ++kc) {
    __syncthreads();
    {
      int sn = t >> 3;
      int node = nbase + sn;
      int kp = (t & 7) * 8;
      bool v = node < nN;
      const float* sp = &x2[(size_t)(v ? node : nN - 1) * 256 + kc * 64 + kp];
      v4 a0 = v ? *(const v4*)(sp + 0) : z;
      v4 a1 = v ? *(const v4*)(sp + 4) : z;
      *(v4*)&xs[sn * 68 + kp + 0] = a0;
      *(v4*)&xs[sn * 68 + kp + 4] = a1;
    }
    {
      int kk = t >> 2;
      int cp = (t & 3) * 16;
      const float* wp = &W2[(size_t)(kc * 64 + kk) * 64 + cp];
      v4 w0 = *(const v4*)(wp + 0);
      v4 w1 = *(const v4*)(wp + 4);
      v4 w2 = *(const v4*)(wp + 8);
      v4 w3 = *(const v4*)(wp + 12);
      *(v4*)&Ws[kk * 64 + cp + 0]  = w0;
      *(v4*)&Ws[kk * 64 + cp + 4]  = w1;
      *(v4*)&Ws[kk * 64 + cp + 8]  = w2;
      *(v4*)&Ws[kk * 64 + cp + 12] = w3;
    }
    __syncthreads();
    #pragma unroll 4
    for (int kk = 0; kk < 64; kk += 4) {
      v4 xv[2], wv[4];
      for (int i = 0; i < 2; ++i) xv[i] = *(const v4*)&xs[(n0 + i) * 68 + kk];
      for (int j = 0; j < 4; ++j) wv[j] = *(const v4*)&Ws[(kk + j) * 64 + c0];
      for (int i = 0; i < 2; ++i)
        for (int j = 0; j < 4; ++j) {
          float xd = xv[i][j];
          acc[i][0] += xd * wv[j][0];
          acc[i][1] += xd * wv[j][1];
          acc[i][2] += xd * wv[j][2];
          acc[i][3] += xd * wv[j][3];
        }
    }
  }
  v4 asl = *(const v4*)&asv[c0];
  v4 adl = *(const v4*)&adv[c0];
  for (int i = 0; i < 2; ++i) {
    int node = nbase + n0 + i;
    v4 o; o[0] = acc[i][0]; o[1] = acc[i][1]; o[2] = acc[i][2]; o[3] = acc[i][3];
    float ps = o[0]*asl[0] + o[1]*asl[1] + o[2]*asl[2] + o[3]*asl[3];
    float pd = o[0]*adl[0] + o[1]*adl[1] + o[2]*adl[2] + o[3]*adl[3];
    ps += __shfl_xor(ps, 1); pd += __shfl_xor(pd, 1);
    ps += __shfl_xor(ps, 2); pd += __shfl_xor(pd, 2);
    ps += __shfl_xor(ps, 4); pd += __shfl_xor(pd, 4);
    ps += __shfl_xor(ps, 8); pd += __shfl_xor(pd, 8);
    if (node < nN) {
      *(v4*)&h2[(size_t)node * 64 + c0] = o;
      if ((t & 15) == 0) { as2[node] = ps; ad2[node] = pd; }
    }
  }
}

// ---- the persistent mega-kernel: all phases, software grid barriers ----
__global__ __launch_bounds__(256, 4) void k_mega(
    const int* __restrict__ nidx, const int* __restrict__ ei,
    const float* __restrict__ emb,
    const float* __restrict__ W1, const float* __restrict__ as1v,
    const float* __restrict__ ad1v, const float* __restrict__ b1,
    const float* __restrict__ W2, const float* __restrict__ as2v,
    const float* __restrict__ ad2v, const float* __restrict__ b2,
    const float* __restrict__ gW1, const float* __restrict__ gb1,
    const float* __restrict__ gW2, const float* __restrict__ gb2,
    float* __restrict__ h1, float* __restrict__ x2, float* __restrict__ h2,
    float* __restrict__ as1, float* __restrict__ ad1,
    float* __restrict__ as2, float* __restrict__ ad2,
    int* __restrict__ rowptr, int* __restrict__ cursor, int* __restrict__ srt,
    int* __restrict__ deg, float* __restrict__ pnum, float* __restrict__ pden,
    int* __restrict__ bar, int* __restrict__ bsum,
    float* __restrict__ out, int nN, int nE, int eT) {
  __shared__ __align__(16) float smem[SMEM_FLOATS];
  const int b = blockIdx.x, t = threadIdx.x, nblk = gridDim.x;
  const int wv = t >> 6, lane = t & 63;

  // ---- P0: degree histogram ----
  for (int e = b * 256 + t; e < eT; e += nblk * 256) {
    int d = (e < nE) ? ei[nE + e] : (e - nE);
    atomicAdd(&deg[d], 1);
  }
  gsync(bar, 1, nblk);

  // ---- P1: per-block chunk sums of deg ----
  const int chunk = (nN + nblk - 1) / nblk;
  int beg = b * chunk; if (beg > nN) beg = nN;
  int end = beg + chunk; if (end > nN) end = nN;
  {
    int part = 0;
    for (int i = beg + t; i < end; i += 256) part += deg[i];
    int* red = (int*)smem;
    red[t] = part; __syncthreads();
    for (int off = 128; off; off >>= 1) { if (t < off) red[t] += red[t + off]; __syncthreads(); }
    if (t == 0) bsum[b] = red[0];
  }
  gsync(bar, 2, nblk);

  // ---- P2: each block computes its prefix offset + writes rowptr/cursor ----
  {
    int part = 0;
    for (int j = t; j < b; j += 256) part += bsum[j];
    int* red = (int*)smem;
    red[t] = part; __syncthreads();
    for (int off = 128; off; off >>= 1) { if (t < off) red[t] += red[t + off]; __syncthreads(); }
    int boff = red[0];
    __syncthreads();
    if (wv == 0) {               // wave 0 scans the chunk in 64-wide steps
      int carry = 0;
      for (int base0 = beg; base0 < end; base0 += 64) {
        int idx = base0 + lane;
        int d = (idx < end) ? deg[idx] : 0;
        int sc = d;
        for (int off = 1; off < 64; off <<= 1) {
          int v = __shfl_up(sc, off);
          if (lane >= off) sc += v;
        }
        if (idx < end) { int v = boff + carry + sc - d; rowptr[idx] = v; cursor[idx] = v; }
        carry += __shfl(sc, 63);
      }
    }
    if (b == 0 && t == 0) rowptr[nN] = eT;
  }
  gsync(bar, 3, nblk);

  // ---- P3: scatter edges (dst-sorted) + gemm1 tiles ----
  for (int e = b * 256 + t; e < eT; e += nblk * 256) {
    int s, d;
    if (e < nE) { s = ei[e]; d = ei[nE + e]; } else { s = d = e - nE; }
    int pos = atomicAdd(&cursor[d], 1);
    srt[pos] = s;
  }
  {
    int ntile = ((nN + 63) >> 6) * 4;
    for (int tile = b; tile < ntile; tile += nblk)
      gemm1_tile(tile, nidx, emb, W1, as1v, ad1v, h1, as1, ad1, nN, smem);
  }
  gsync(bar, 4, nblk);

  // ---- P4: layer-1 softmax + aggregate + bias + ELU (one wave per node) ----
  {
    int*   ss = (int*)smem;       // [4][64]
    float* sw = smem + 256;       // [4][256]
    int*   ssw = ss + wv * 64;
    float* sww = sw + wv * 256;
    for (int n = b * 4 + wv; n < nN; n += nblk * 4) {
      int ms0 = rowptr[n], ms1 = rowptr[n + 1];
      v4 adn = *(const v4*)&ad1[(size_t)n * 4];
      int h = lane >> 4;
      v4 acc = (v4)(0.f);
      float den = 0.f;
      for (int base0 = ms0; base0 < ms1; base0 += 64) {
        int m = ms1 - base0; if (m > 64) m = 64;
        WAITLDS();
        if (lane < m) {
          int s = srt[base0 + lane];
          ssw[lane] = s;
          v4 a = *(const v4*)&as1[(size_t)s * 4];
          sww[lane * 4 + 0] = __expf(leaky(a[0] + adn[0]));
          sww[lane * 4 + 1] = __expf(leaky(a[1] + adn[1]));
          sww[lane * 4 + 2] = __expf(leaky(a[2] + adn[2]));
          sww[lane * 4 + 3] = __expf(leaky(a[3] + adn[3]));
        }
        WAITLDS();
        #pragma unroll 8
        for (int j = 0; j < m; ++j) {
          int s = ssw[j];
          float wj = sww[j * 4 + h];
          v4 hv = *(const v4*)&h1[(size_t)s * 256 + lane * 4];
          acc[0] += wj * hv[0];
          acc[1] += wj * hv[1];
          acc[2] += wj * hv[2];
          acc[3] += wj * hv[3];
          den += wj;
        }
      }
      v4 bb = *(const v4*)&b1[lane * 4];
      float inv = 1.f / den;
      v4 o;
      o[0] = elu(acc[0] * inv + bb[0]);
      o[1] = elu(acc[1] * inv + bb[1]);
      o[2] = elu(acc[2] * inv + bb[2]);
      o[3] = elu(acc[3] * inv + bb[3]);
      *(v4*)&x2[(size_t)n * 256 + lane * 4] = o;
    }
  }
  gsync(bar, 5, nblk);

  // ---- P5: gemm2 tiles ----
  {
    int ntile2 = (nN + 31) >> 5;
    for (int tile = b; tile < ntile2; tile += nblk)
      gemm2_tile(tile, x2, W2, as2v, ad2v, h2, as2, ad2, nN, smem);
  }
  gsync(bar, 6, nblk);

  // ---- P6: fused layer-2 aggregate + ELU + gate MLP + pooled partials ----
  {
    float* gwT  = smem;                     // 64*68 = 4352
    int*   ssT  = (int*)(smem + 4352);      // [4][64]
    float* swT  = smem + 4352 + 256;        // [4][64]
    float* xrT  = smem + 4352 + 512;        // [4][64]
    float* snum = smem + 4352 + 768;        // [4][64]
    float* sden = smem + 4352 + 1024;       // [4]
    for (int i = t; i < 4096; i += 256) {
      int d = i >> 6, c = i & 63;
      gwT[c * 68 + d] = gW1[i];
    }
    float gb1l = gb1[lane], gw2l = gW2[lane], gb2s = gb2[0], b2l = b2[lane];
    __syncthreads();
    int*   ssw = ssT + wv * 64;
    float* sww = swT + wv * 64;
    float* xrw = xrT + wv * 64;
    float num = 0.f, denp = 0.f;
    for (int n = b * 4 + wv; n < nN; n += nblk * 4) {
      int ms0 = rowptr[n], ms1 = rowptr[n + 1];
      float adn = ad2[n];
      float acc = 0.f, den = 0.f;
      for (int base0 = ms0; base0 < ms1; base0 += 64) {
        int m = ms1 - base0; if (m > 64) m = 64;
        WAITLDS();
        if (lane < m) {
          int s = srt[base0 + lane];
          ssw[lane] = s;
          sww[lane] = __expf(leaky(as2[s] + adn));
        }
        WAITLDS();
        #pragma unroll 8
        for (int j = 0; j < m; ++j) {
          int s = ssw[j];
          float wj = sww[j];
          acc += wj * h2[(size_t)s * 64 + lane];
          den += wj;
        }
      }
      float x3v = elu(acc / den + b2l);
      WAITLDS();
      xrw[lane] = x3v;
      WAITLDS();
      float hid = gb1l;
      for (int d4 = 0; d4 < 64; d4 += 4) {
        v4 xs4 = *(const v4*)&xrw[d4];
        v4 gv  = *(const v4*)&gwT[lane * 68 + d4];
        hid += xs4[0] * gv[0] + xs4[1] * gv[1] + xs4[2] * gv[2] + xs4[3] * gv[3];
      }
      hid = fmaxf(hid, 0.f);
      float p = hid * gw2l;
      for (int o = 32; o; o >>= 1) p += __shfl_xor(p, o);
      float g = __expf(p + gb2s);
      num += g * x3v;
      denp += g;
    }
    snum[wv * 64 + lane] = num;
    if (lane == 0) sden[wv] = denp;
    __syncthreads();
    if (t < 64) atomicAdd(&pnum[t], snum[t] + snum[64 + t] + snum[128 + t] + snum[192 + t]);
    if (t == 0) atomicAdd(pden, sden[0] + sden[1] + sden[2] + sden[3]);
  }
  gsync(bar, 7, nblk);

  // ---- P7: final output (block 0) ----
  if (b == 0 && t < 64) {
    float nv = atomicAdd(&pnum[t], 0.f);   // coherent device-scope read
    float dv = atomicAdd(pden, 0.f);
    out[t] = nv / dv;
  }
}

extern "C" void kernel_launch(void* const* d_in, const int* in_sizes, int n_in,
                              void* d_out, int out_size, void* d_ws, size_t ws_size,
                              hipStream_t stream) {
  const int*   nidx = (const int*)d_in[0];
  const int*   ei   = (const int*)d_in[1];
  const float* emb  = (const float*)d_in[2];
  const float* W1   = (const float*)d_in[3];
  const float* as1v = (const float*)d_in[4];
  const float* ad1v = (const float*)d_in[5];
  const float* b1   = (const float*)d_in[6];
  const float* W2   = (const float*)d_in[7];
  const float* as2v = (const float*)d_in[8];
  const float* ad2v = (const float*)d_in[9];
  const float* b2   = (const float*)d_in[10];
  const float* gW1  = (const float*)d_in[11];
  const float* gb1  = (const float*)d_in[12];
  const float* gW2  = (const float*)d_in[13];
  const float* gb2  = (const float*)d_in[14];
  float* out = (float*)d_out;

  const int nN = in_sizes[0];
  const int nE = in_sizes[1] / 2;
  const int eT = nE + nN;

  float* f = (float*)d_ws;
  size_t off = 0;
  float* h1   = f + off; off += (size_t)nN * 256;
  float* x2   = f + off; off += (size_t)nN * 256;
  float* as1  = f + off; off += (size_t)nN * 4;
  float* ad1  = f + off; off += (size_t)nN * 4;
  float* as2  = f + off; off += nN;
  float* ad2  = f + off; off += nN;
  int* rowptr = (int*)(f + off); off += nN + 1;
  int* cursor = (int*)(f + off); off += nN;
  int* srt    = (int*)(f + off); off += eT;
  // zeroed region: [deg | pnum | pden | bar]  (nN + 66 ints)
  int*   deg  = (int*)(f + off); size_t zoff = off; off += nN;
  float* pnum = f + off; off += 64;
  float* pden = f + off; off += 1;
  int*   bar  = (int*)(f + off); off += 1;
  int*   bsum = (int*)(f + off); off += 4096;
  // optional dedicated h2 (avoids aliasing h1's cached lines); fall back to alias
  float* h2 = h1;
  if ((off + (size_t)nN * 64) * sizeof(float) <= ws_size) {
    h2 = f + off; off += (size_t)nN * 64;
  }

  hipMemsetAsync(deg, 0, (size_t)(nN + 66) * sizeof(int), stream);
  (void)zoff;

  // grid sized for guaranteed co-residency (software grid barrier requirement)
  int dev = 0; hipGetDevice(&dev);
  int numCU = 256;
  hipDeviceGetAttribute(&numCU, hipDeviceAttributeMultiprocessorCount, dev);
  int bpc = 0;
  hipOccupancyMaxActiveBlocksPerMultiprocessor(&bpc, (const void*)k_mega, 256, 0);
  if (bpc < 1) bpc = 1;
  if (bpc > 4) bpc = 4;
  int grid = numCU * bpc;
  if (grid > 4096) grid = 4096;   // bsum capacity

  k_mega<<<grid, 256, 0, stream>>>(nidx, ei, emb,
                                   W1, as1v, ad1v, b1,
                                   W2, as2v, ad2v, b2,
                                   gW1, gb1, gW2, gb2,
                                   h1, x2, h2, as1, ad1, as2, ad2,
                                   rowptr, cursor, srt, deg, pnum, pden,
                                   bar, bsum, out, nN, nE, eT);
}

// Round 8
// 779.489 us; speedup vs baseline: 1.0128x; 1.0128x over previous
//
#include <hip/hip_runtime.h>

typedef float v4 __attribute__((ext_vector_type(4)));

__device__ __forceinline__ float leaky(float x) { return x >= 0.f ? x : 0.2f * x; }
__device__ __forceinline__ float elu(float x) { return x > 0.f ? x : expm1f(x); }

#define WAITLDS() do { asm volatile("s_waitcnt lgkmcnt(0)" ::: "memory"); \
                       __builtin_amdgcn_wave_barrier(); } while (0)

// union scratch: gemm1 needs 64*68 + 64*64 = 8448 floats = 33792 B (largest phase)
#define SMEM_FLOATS (64 * 68 + 64 * 64)

// ---- software grid barrier: monotone counter, device-scope ----
// CRITICAL (round-7 lesson): the POLL must be an atomic RMW. A plain agent-scope
// load can be served from a stale line in the local XCD's L2 (per-XCD L2s are not
// cross-coherent; buffer_inv covers L1), stalling ~140us until eviction. RMWs
// always execute at the coherent point.
__device__ __forceinline__ void gsync(int* bar, int phase, int nblk) {
  __syncthreads();
  if (threadIdx.x == 0) {
    __threadfence();   // release: wbl2 — flush this XCD's dirty L2 device-wide
    __hip_atomic_fetch_add(bar, 1, __ATOMIC_RELEASE, __HIP_MEMORY_SCOPE_AGENT);
    const int target = phase * nblk;
    while (__hip_atomic_fetch_add(bar, 0, __ATOMIC_ACQUIRE,
                                  __HIP_MEMORY_SCOPE_AGENT) < target)
      __builtin_amdgcn_s_sleep(64);   // ~4096 cyc backoff between coherent polls
    __threadfence();   // acquire: inv — drop stale L1/L2 lines before next phase
  }
  __syncthreads();
}

// ---- GEMM1 tile: h1[n,256] = emb[nidx[n],128] @ W1[128,256] + alpha epilogue ----
__device__ __forceinline__ void gemm1_tile(
    int tile, const int* __restrict__ nidx, const float* __restrict__ emb,
    const float* __restrict__ W1, const float* __restrict__ asv,
    const float* __restrict__ adv, float* __restrict__ h1,
    float* __restrict__ as1, float* __restrict__ ad1, int nN, float* smem) {
  float* xs = smem;             // 64*68
  float* Ws = smem + 64 * 68;   // 64*64
  int t = threadIdx.x;
  int nbase = (tile >> 2) * 64;
  int head  = tile & 3;
  int cbase = head * 64;
  int c0 = (t & 15) * 4;
  int n0 = (t >> 4) * 4;
  float acc[4][4];
  for (int i = 0; i < 4; ++i) for (int j = 0; j < 4; ++j) acc[i][j] = 0.f;
  v4 z = (v4)(0.f);
  for (int kc = 0; kc < 2; ++kc) {
    __syncthreads();
    {
      int sn = t >> 2;
      int node = nbase + sn;
      int kp = (t & 3) * 16;
      bool v = node < nN;
      const float* sp = &emb[(size_t)nidx[v ? node : nN - 1] * 128 + kc * 64 + kp];
      v4 a0 = v ? *(const v4*)(sp + 0)  : z;
      v4 a1 = v ? *(const v4*)(sp + 4)  : z;
      v4 a2 = v ? *(const v4*)(sp + 8)  : z;
      v4 a3 = v ? *(const v4*)(sp + 12) : z;
      *(v4*)&xs[sn * 68 + kp + 0]  = a0;
      *(v4*)&xs[sn * 68 + kp + 4]  = a1;
      *(v4*)&xs[sn * 68 + kp + 8]  = a2;
      *(v4*)&xs[sn * 68 + kp + 12] = a3;
    }
    {
      int kk = t >> 2;
      int cp = (t & 3) * 16;
      const float* wp = &W1[(size_t)(kc * 64 + kk) * 256 + cbase + cp];
      v4 w0 = *(const v4*)(wp + 0);
      v4 w1 = *(const v4*)(wp + 4);
      v4 w2 = *(const v4*)(wp + 8);
      v4 w3 = *(const v4*)(wp + 12);
      *(v4*)&Ws[kk * 64 + cp + 0]  = w0;
      *(v4*)&Ws[kk * 64 + cp + 4]  = w1;
      *(v4*)&Ws[kk * 64 + cp + 8]  = w2;
      *(v4*)&Ws[kk * 64 + cp + 12] = w3;
    }
    __syncthreads();
    #pragma unroll 4
    for (int kk = 0; kk < 64; kk += 4) {
      v4 xv[4], wv[4];
      for (int i = 0; i < 4; ++i) xv[i] = *(const v4*)&xs[(n0 + i) * 68 + kk];
      for (int j = 0; j < 4; ++j) wv[j] = *(const v4*)&Ws[(kk + j) * 64 + c0];
      for (int i = 0; i < 4; ++i)
        for (int j = 0; j < 4; ++j) {
          float xd = xv[i][j];
          acc[i][0] += xd * wv[j][0];
          acc[i][1] += xd * wv[j][1];
          acc[i][2] += xd * wv[j][2];
          acc[i][3] += xd * wv[j][3];
        }
    }
  }
  v4 asl = *(const v4*)&asv[cbase + c0];
  v4 adl = *(const v4*)&adv[cbase + c0];
  for (int i = 0; i < 4; ++i) {
    int node = nbase + n0 + i;
    v4 o; o[0] = acc[i][0]; o[1] = acc[i][1]; o[2] = acc[i][2]; o[3] = acc[i][3];
    float ps = o[0]*asl[0] + o[1]*asl[1] + o[2]*asl[2] + o[3]*asl[3];
    float pd = o[0]*adl[0] + o[1]*adl[1] + o[2]*adl[2] + o[3]*adl[3];
    ps += __shfl_xor(ps, 1); pd += __shfl_xor(pd, 1);
    ps += __shfl_xor(ps, 2); pd += __shfl_xor(pd, 2);
    ps += __shfl_xor(ps, 4); pd += __shfl_xor(pd, 4);
    ps += __shfl_xor(ps, 8); pd += __shfl_xor(pd, 8);
    if (node < nN) {
      *(v4*)&h1[(size_t)node * 256 + cbase + c0] = o;
      if ((t & 15) == 0) {
        as1[(size_t)node * 4 + head] = ps;
        ad1[(size_t)node * 4 + head] = pd;
      }
    }
  }
}

// ---- GEMM2 tile: h2[n,64] = x2[n,256] @ W2[256,64] + alpha epilogue ----
__device__ __forceinline__ void gemm2_tile(
    int tile, const float* __restrict__ x2, const float* __restrict__ W2,
    const float* __restrict__ asv, const float* __restrict__ adv,
    float* __restrict__ h2, float* __restrict__ as2, float* __restrict__ ad2,
    int nN, float* smem) {
  float* xs = smem;             // 32*68
  float* Ws = smem + 32 * 68;   // 64*64
  int t = threadIdx.x;
  int nbase = tile * 32;
  int c0 = (t & 15) * 4;
  int n0 = (t >> 4) * 2;
  float acc[2][4];
  for (int i = 0; i < 2; ++i) for (int j = 0; j < 4; ++j) acc[i][j] = 0.f;
  v4 z = (v4)(0.f);
  for (int kc = 0; kc < 4; ++kc) {
    __syncthreads();
    {
      int sn = t >> 3;
      int node = nbase + sn;
      int kp = (t & 7) * 8;
      bool v = node < nN;
      const float* sp = &x2[(size_t)(v ? node : nN - 1) * 256 + kc * 64 + kp];
      v4 a0 = v ? *(const v4*)(sp + 0) : z;
      v4 a1 = v ? *(const v4*)(sp + 4) : z;
      *(v4*)&xs[sn * 68 + kp + 0] = a0;
      *(v4*)&xs[sn * 68 + kp + 4] = a1;
    }
    {
      int kk = t >> 2;
      int cp = (t & 3) * 16;
      const float* wp = &W2[(size_t)(kc * 64 + kk) * 64 + cp];
      v4 w0 = *(const v4*)(wp + 0);
      v4 w1 = *(const v4*)(wp + 4);
      v4 w2 = *(const v4*)(wp + 8);
      v4 w3 = *(const v4*)(wp + 12);
      *(v4*)&Ws[kk * 64 + cp + 0]  = w0;
      *(v4*)&Ws[kk * 64 + cp + 4]  = w1;
      *(v4*)&Ws[kk * 64 + cp + 8]  = w2;
      *(v4*)&Ws[kk * 64 + cp + 12] = w3;
    }
    __syncthreads();
    #pragma unroll 4
    for (int kk = 0; kk < 64; kk += 4) {
      v4 xv[2], wv[4];
      for (int i = 0; i < 2; ++i) xv[i] = *(const v4*)&xs[(n0 + i) * 68 + kk];
      for (int j = 0; j < 4; ++j) wv[j] = *(const v4*)&Ws[(kk + j) * 64 + c0];
      for (int i = 0; i < 2; ++i)
        for (int j = 0; j < 4; ++j) {
          float xd = xv[i][j];
          acc[i][0] += xd * wv[j][0];
          acc[i][1] += xd * wv[j][1];
          acc[i][2] += xd * wv[j][2];
          acc[i][3] += xd * wv[j][3];
        }
    }
  }
  v4 asl = *(const v4*)&asv[c0];
  v4 adl = *(const v4*)&adv[c0];
  for (int i = 0; i < 2; ++i) {
    int node = nbase + n0 + i;
    v4 o; o[0] = acc[i][0]; o[1] = acc[i][1]; o[2] = acc[i][2]; o[3] = acc[i][3];
    float ps = o[0]*asl[0] + o[1]*asl[1] + o[2]*asl[2] + o[3]*asl[3];
    float pd = o[0]*adl[0] + o[1]*adl[1] + o[2]*adl[2] + o[3]*adl[3];
    ps += __shfl_xor(ps, 1); pd += __shfl_xor(pd, 1);
    ps += __shfl_xor(ps, 2); pd += __shfl_xor(pd, 2);
    ps += __shfl_xor(ps, 4); pd += __shfl_xor(pd, 4);
    ps += __shfl_xor(ps, 8); pd += __shfl_xor(pd, 8);
    if (node < nN) {
      *(v4*)&h2[(size_t)node * 64 + c0] = o;
      if ((t & 15) == 0) { as2[node] = ps; ad2[node] = pd; }
    }
  }
}

// ---- the persistent mega-kernel: all phases, software grid barriers ----
__global__ __launch_bounds__(256, 4) void k_mega(
    const int* __restrict__ nidx, const int* __restrict__ ei,
    const float* __restrict__ emb,
    const float* __restrict__ W1, const float* __restrict__ as1v,
    const float* __restrict__ ad1v, const float* __restrict__ b1,
    const float* __restrict__ W2, const float* __restrict__ as2v,
    const float* __restrict__ ad2v, const float* __restrict__ b2,
    const float* __restrict__ gW1, const float* __restrict__ gb1,
    const float* __restrict__ gW2, const float* __restrict__ gb2,
    float* __restrict__ h1, float* __restrict__ x2, float* __restrict__ h2,
    float* __restrict__ as1, float* __restrict__ ad1,
    float* __restrict__ as2, float* __restrict__ ad2,
    int* __restrict__ rowptr, int* __restrict__ cursor, int* __restrict__ srt,
    int* __restrict__ deg, float* __restrict__ pnum, float* __restrict__ pden,
    int* __restrict__ bar, int* __restrict__ bsum,
    float* __restrict__ out, int nN, int nE, int eT) {
  __shared__ __align__(16) float smem[SMEM_FLOATS];
  const int b = blockIdx.x, t = threadIdx.x, nblk = gridDim.x;
  const int wv = t >> 6, lane = t & 63;

  // ---- P0: degree histogram ----
  for (int e = b * 256 + t; e < eT; e += nblk * 256) {
    int d = (e < nE) ? ei[nE + e] : (e - nE);
    atomicAdd(&deg[d], 1);
  }
  gsync(bar, 1, nblk);

  // ---- P1: per-block chunk sums of deg ----
  const int chunk = (nN + nblk - 1) / nblk;
  int beg = b * chunk; if (beg > nN) beg = nN;
  int end = beg + chunk; if (end > nN) end = nN;
  {
    int part = 0;
    for (int i = beg + t; i < end; i += 256) part += deg[i];
    int* red = (int*)smem;
    red[t] = part; __syncthreads();
    for (int off = 128; off; off >>= 1) { if (t < off) red[t] += red[t + off]; __syncthreads(); }
    if (t == 0) bsum[b] = red[0];
  }
  gsync(bar, 2, nblk);

  // ---- P2: each block computes its prefix offset + writes rowptr/cursor ----
  {
    int part = 0;
    for (int j = t; j < b; j += 256) part += bsum[j];
    int* red = (int*)smem;
    red[t] = part; __syncthreads();
    for (int off = 128; off; off >>= 1) { if (t < off) red[t] += red[t + off]; __syncthreads(); }
    int boff = red[0];
    __syncthreads();
    if (wv == 0) {               // wave 0 scans the chunk in 64-wide steps
      int carry = 0;
      for (int base0 = beg; base0 < end; base0 += 64) {
        int idx = base0 + lane;
        int d = (idx < end) ? deg[idx] : 0;
        int sc = d;
        for (int off = 1; off < 64; off <<= 1) {
          int v = __shfl_up(sc, off);
          if (lane >= off) sc += v;
        }
        if (idx < end) { int v = boff + carry + sc - d; rowptr[idx] = v; cursor[idx] = v; }
        carry += __shfl(sc, 63);
      }
    }
    if (b == 0 && t == 0) rowptr[nN] = eT;
  }
  gsync(bar, 3, nblk);

  // ---- P3: scatter edges (dst-sorted) + gemm1 tiles ----
  for (int e = b * 256 + t; e < eT; e += nblk * 256) {
    int s, d;
    if (e < nE) { s = ei[e]; d = ei[nE + e]; } else { s = d = e - nE; }
    int pos = atomicAdd(&cursor[d], 1);
    srt[pos] = s;
  }
  {
    int ntile = ((nN + 63) >> 6) * 4;
    for (int tile = b; tile < ntile; tile += nblk)
      gemm1_tile(tile, nidx, emb, W1, as1v, ad1v, h1, as1, ad1, nN, smem);
  }
  gsync(bar, 4, nblk);

  // ---- P4: layer-1 softmax + aggregate + bias + ELU (one wave per node) ----
  {
    int*   ss = (int*)smem;       // [4][64]
    float* sw = smem + 256;       // [4][256]
    int*   ssw = ss + wv * 64;
    float* sww = sw + wv * 256;
    for (int n = b * 4 + wv; n < nN; n += nblk * 4) {
      int ms0 = rowptr[n], ms1 = rowptr[n + 1];
      v4 adn = *(const v4*)&ad1[(size_t)n * 4];
      int h = lane >> 4;
      v4 acc = (v4)(0.f);
      float den = 0.f;
      for (int base0 = ms0; base0 < ms1; base0 += 64) {
        int m = ms1 - base0; if (m > 64) m = 64;
        WAITLDS();
        if (lane < m) {
          int s = srt[base0 + lane];
          ssw[lane] = s;
          v4 a = *(const v4*)&as1[(size_t)s * 4];
          sww[lane * 4 + 0] = __expf(leaky(a[0] + adn[0]));
          sww[lane * 4 + 1] = __expf(leaky(a[1] + adn[1]));
          sww[lane * 4 + 2] = __expf(leaky(a[2] + adn[2]));
          sww[lane * 4 + 3] = __expf(leaky(a[3] + adn[3]));
        }
        WAITLDS();
        #pragma unroll 8
        for (int j = 0; j < m; ++j) {
          int s = ssw[j];
          float wj = sww[j * 4 + h];
          v4 hv = *(const v4*)&h1[(size_t)s * 256 + lane * 4];
          acc[0] += wj * hv[0];
          acc[1] += wj * hv[1];
          acc[2] += wj * hv[2];
          acc[3] += wj * hv[3];
          den += wj;
        }
      }
      v4 bb = *(const v4*)&b1[lane * 4];
      float inv = 1.f / den;
      v4 o;
      o[0] = elu(acc[0] * inv + bb[0]);
      o[1] = elu(acc[1] * inv + bb[1]);
      o[2] = elu(acc[2] * inv + bb[2]);
      o[3] = elu(acc[3] * inv + bb[3]);
      *(v4*)&x2[(size_t)n * 256 + lane * 4] = o;
    }
  }
  gsync(bar, 5, nblk);

  // ---- P5: gemm2 tiles ----
  {
    int ntile2 = (nN + 31) >> 5;
    for (int tile = b; tile < ntile2; tile += nblk)
      gemm2_tile(tile, x2, W2, as2v, ad2v, h2, as2, ad2, nN, smem);
  }
  gsync(bar, 6, nblk);

  // ---- P6: fused layer-2 aggregate + ELU + gate MLP + pooled partials ----
  {
    float* gwT  = smem;                     // 64*68 = 4352
    int*   ssT  = (int*)(smem + 4352);      // [4][64]
    float* swT  = smem + 4352 + 256;        // [4][64]
    float* xrT  = smem + 4352 + 512;        // [4][64]
    float* snum = smem + 4352 + 768;        // [4][64]
    float* sden = smem + 4352 + 1024;       // [4]
    for (int i = t; i < 4096; i += 256) {
      int d = i >> 6, c = i & 63;
      gwT[c * 68 + d] = gW1[i];
    }
    float gb1l = gb1[lane], gw2l = gW2[lane], gb2s = gb2[0], b2l = b2[lane];
    __syncthreads();
    int*   ssw = ssT + wv * 64;
    float* sww = swT + wv * 64;
    float* xrw = xrT + wv * 64;
    float num = 0.f, denp = 0.f;
    for (int n = b * 4 + wv; n < nN; n += nblk * 4) {
      int ms0 = rowptr[n], ms1 = rowptr[n + 1];
      float adn = ad2[n];
      float acc = 0.f, den = 0.f;
      for (int base0 = ms0; base0 < ms1; base0 += 64) {
        int m = ms1 - base0; if (m > 64) m = 64;
        WAITLDS();
        if (lane < m) {
          int s = srt[base0 + lane];
          ssw[lane] = s;
          sww[lane] = __expf(leaky(as2[s] + adn));
        }
        WAITLDS();
        #pragma unroll 8
        for (int j = 0; j < m; ++j) {
          int s = ssw[j];
          float wj = sww[j];
          acc += wj * h2[(size_t)s * 64 + lane];
          den += wj;
        }
      }
      float x3v = elu(acc / den + b2l);
      WAITLDS();
      xrw[lane] = x3v;
      WAITLDS();
      float hid = gb1l;
      for (int d4 = 0; d4 < 64; d4 += 4) {
        v4 xs4 = *(const v4*)&xrw[d4];
        v4 gv  = *(const v4*)&gwT[lane * 68 + d4];
        hid += xs4[0] * gv[0] + xs4[1] * gv[1] + xs4[2] * gv[2] + xs4[3] * gv[3];
      }
      hid = fmaxf(hid, 0.f);
      float p = hid * gw2l;
      for (int o = 32; o; o >>= 1) p += __shfl_xor(p, o);
      float g = __expf(p + gb2s);
      num += g * x3v;
      denp += g;
    }
    snum[wv * 64 + lane] = num;
    if (lane == 0) sden[wv] = denp;
    __syncthreads();
    if (t < 64) atomicAdd(&pnum[t], snum[t] + snum[64 + t] + snum[128 + t] + snum[192 + t]);
    if (t == 0) atomicAdd(pden, sden[0] + sden[1] + sden[2] + sden[3]);
  }
  gsync(bar, 7, nblk);

  // ---- P7: final output (block 0) ----
  if (b == 0 && t < 64) {
    float nv = atomicAdd(&pnum[t], 0.f);   // coherent device-scope read
    float dv = atomicAdd(pden, 0.f);
    out[t] = nv / dv;
  }
}

extern "C" void kernel_launch(void* const* d_in, const int* in_sizes, int n_in,
                              void* d_out, int out_size, void* d_ws, size_t ws_size,
                              hipStream_t stream) {
  const int*   nidx = (const int*)d_in[0];
  const int*   ei   = (const int*)d_in[1];
  const float* emb  = (const float*)d_in[2];
  const float* W1   = (const float*)d_in[3];
  const float* as1v = (const float*)d_in[4];
  const float* ad1v = (const float*)d_in[5];
  const float* b1   = (const float*)d_in[6];
  const float* W2   = (const float*)d_in[7];
  const float* as2v = (const float*)d_in[8];
  const float* ad2v = (const float*)d_in[9];
  const float* b2   = (const float*)d_in[10];
  const float* gW1  = (const float*)d_in[11];
  const float* gb1  = (const float*)d_in[12];
  const float* gW2  = (const float*)d_in[13];
  const float* gb2  = (const float*)d_in[14];
  float* out = (float*)d_out;

  const int nN = in_sizes[0];
  const int nE = in_sizes[1] / 2;
  const int eT = nE + nN;

  float* f = (float*)d_ws;
  size_t off = 0;
  float* h1   = f + off; off += (size_t)nN * 256;
  float* x2   = f + off; off += (size_t)nN * 256;
  float* as1  = f + off; off += (size_t)nN * 4;
  float* ad1  = f + off; off += (size_t)nN * 4;
  float* as2  = f + off; off += nN;
  float* ad2  = f + off; off += nN;
  int* rowptr = (int*)(f + off); off += nN + 1;
  int* cursor = (int*)(f + off); off += nN;
  int* srt    = (int*)(f + off); off += eT;
  // zeroed region: [deg | pnum | pden | bar]  (nN + 66 ints)
  int*   deg  = (int*)(f + off); off += nN;
  float* pnum = f + off; off += 64;
  float* pden = f + off; off += 1;
  int*   bar  = (int*)(f + off); off += 1;
  int*   bsum = (int*)(f + off); off += 4096;
  // dedicated h2 (avoids aliasing h1's cached lines) when workspace allows
  float* h2 = h1;
  if ((off + (size_t)nN * 64) * sizeof(float) <= ws_size) {
    h2 = f + off; off += (size_t)nN * 64;
  }

  hipMemsetAsync(deg, 0, (size_t)(nN + 66) * sizeof(int), stream);

  // grid sized for guaranteed co-residency (software grid barrier requirement)
  int dev = 0; hipGetDevice(&dev);
  int numCU = 256;
  hipDeviceGetAttribute(&numCU, hipDeviceAttributeMultiprocessorCount, dev);
  int bpc = 0;
  hipOccupancyMaxActiveBlocksPerMultiprocessor(&bpc, (const void*)k_mega, 256, 0);
  if (bpc < 1) bpc = 1;
  if (bpc > 4) bpc = 4;
  int grid = numCU * bpc;
  if (grid > 4096) grid = 4096;   // bsum capacity

  k_mega<<<grid, 256, 0, stream>>>(nidx, ei, emb,
                                   W1, as1v, ad1v, b1,
                                   W2, as2v, ad2v, b2,
                                   gW1, gb1, gW2, gb2,
                                   h1, x2, h2, as1, ad1, as2, ad2,
                                   rowptr, cursor, srt, deg, pnum, pden,
                                   bar, bsum, out, nN, nE, eT);
}

// Round 9
// 684.335 us; speedup vs baseline: 1.1536x; 1.1390x over previous
//
#include <hip/hip_runtime.h>

typedef float v4 __attribute__((ext_vector_type(4)));

__device__ __forceinline__ float leaky(float x) { return x >= 0.f ? x : 0.2f * x; }
__device__ __forceinline__ float elu(float x) { return x > 0.f ? x : expm1f(x); }

#define WAITLDS() do { asm volatile("s_waitcnt lgkmcnt(0)" ::: "memory"); \
                       __builtin_amdgcn_wave_barrier(); } while (0)

// union scratch: gemm1 needs 64*68 + 64*64 = 8448 floats = 33792 B (largest phase)
#define SMEM_FLOATS (64 * 68 + 64 * 64)

// ---- software grid barrier ----
// Round-8 lesson: ACQUIRE-flavored polls (load or RMW) emit a buffer_inv PER POLL
// ITERATION, so early-arriving blocks continuously nuke their XCD's L1/L2 while
// stragglers still compute — 10x phase slowdown. Poll must be RELAXED (compiles to
// global_load sc1 = reads the coherent point, no invalidate, no stale-L2 livelock);
// do exactly ONE acquire fence after the loop exits.
__device__ __forceinline__ void gsync(int* bar, int phase, int nblk) {
  __syncthreads();
  if (threadIdx.x == 0) {
    __threadfence();   // release: write back this block's stores device-wide
    __hip_atomic_fetch_add(bar, 1, __ATOMIC_RELEASE, __HIP_MEMORY_SCOPE_AGENT);
    const int target = phase * nblk;
    while (__hip_atomic_load(bar, __ATOMIC_RELAXED, __HIP_MEMORY_SCOPE_AGENT) < target)
      __builtin_amdgcn_s_sleep(8);    // ~512 cyc backoff; poll is a cheap sc1 load
    __threadfence();   // acquire: ONE invalidate before consuming the next phase's data
  }
  __syncthreads();
}

// ---- GEMM1 tile: h1[n,256] = emb[nidx[n],128] @ W1[128,256] + alpha epilogue ----
__device__ __forceinline__ void gemm1_tile(
    int tile, const int* __restrict__ nidx, const float* __restrict__ emb,
    const float* __restrict__ W1, const float* __restrict__ asv,
    const float* __restrict__ adv, float* __restrict__ h1,
    float* __restrict__ as1, float* __restrict__ ad1, int nN, float* smem) {
  float* xs = smem;             // 64*68
  float* Ws = smem + 64 * 68;   // 64*64
  int t = threadIdx.x;
  int nbase = (tile >> 2) * 64;
  int head  = tile & 3;
  int cbase = head * 64;
  int c0 = (t & 15) * 4;
  int n0 = (t >> 4) * 4;
  float acc[4][4];
  for (int i = 0; i < 4; ++i) for (int j = 0; j < 4; ++j) acc[i][j] = 0.f;
  v4 z = (v4)(0.f);
  for (int kc = 0; kc < 2; ++kc) {
    __syncthreads();
    {
      int sn = t >> 2;
      int node = nbase + sn;
      int kp = (t & 3) * 16;
      bool v = node < nN;
      const float* sp = &emb[(size_t)nidx[v ? node : nN - 1] * 128 + kc * 64 + kp];
      v4 a0 = v ? *(const v4*)(sp + 0)  : z;
      v4 a1 = v ? *(const v4*)(sp + 4)  : z;
      v4 a2 = v ? *(const v4*)(sp + 8)  : z;
      v4 a3 = v ? *(const v4*)(sp + 12) : z;
      *(v4*)&xs[sn * 68 + kp + 0]  = a0;
      *(v4*)&xs[sn * 68 + kp + 4]  = a1;
      *(v4*)&xs[sn * 68 + kp + 8]  = a2;
      *(v4*)&xs[sn * 68 + kp + 12] = a3;
    }
    {
      int kk = t >> 2;
      int cp = (t & 3) * 16;
      const float* wp = &W1[(size_t)(kc * 64 + kk) * 256 + cbase + cp];
      v4 w0 = *(const v4*)(wp + 0);
      v4 w1 = *(const v4*)(wp + 4);
      v4 w2 = *(const v4*)(wp + 8);
      v4 w3 = *(const v4*)(wp + 12);
      *(v4*)&Ws[kk * 64 + cp + 0]  = w0;
      *(v4*)&Ws[kk * 64 + cp + 4]  = w1;
      *(v4*)&Ws[kk * 64 + cp + 8]  = w2;
      *(v4*)&Ws[kk * 64 + cp + 12] = w3;
    }
    __syncthreads();
    #pragma unroll 4
    for (int kk = 0; kk < 64; kk += 4) {
      v4 xv[4], wv[4];
      for (int i = 0; i < 4; ++i) xv[i] = *(const v4*)&xs[(n0 + i) * 68 + kk];
      for (int j = 0; j < 4; ++j) wv[j] = *(const v4*)&Ws[(kk + j) * 64 + c0];
      for (int i = 0; i < 4; ++i)
        for (int j = 0; j < 4; ++j) {
          float xd = xv[i][j];
          acc[i][0] += xd * wv[j][0];
          acc[i][1] += xd * wv[j][1];
          acc[i][2] += xd * wv[j][2];
          acc[i][3] += xd * wv[j][3];
        }
    }
  }
  v4 asl = *(const v4*)&asv[cbase + c0];
  v4 adl = *(const v4*)&adv[cbase + c0];
  for (int i = 0; i < 4; ++i) {
    int node = nbase + n0 + i;
    v4 o; o[0] = acc[i][0]; o[1] = acc[i][1]; o[2] = acc[i][2]; o[3] = acc[i][3];
    float ps = o[0]*asl[0] + o[1]*asl[1] + o[2]*asl[2] + o[3]*asl[3];
    float pd = o[0]*adl[0] + o[1]*adl[1] + o[2]*adl[2] + o[3]*adl[3];
    ps += __shfl_xor(ps, 1); pd += __shfl_xor(pd, 1);
    ps += __shfl_xor(ps, 2); pd += __shfl_xor(pd, 2);
    ps += __shfl_xor(ps, 4); pd += __shfl_xor(pd, 4);
    ps += __shfl_xor(ps, 8); pd += __shfl_xor(pd, 8);
    if (node < nN) {
      *(v4*)&h1[(size_t)node * 256 + cbase + c0] = o;
      if ((t & 15) == 0) {
        as1[(size_t)node * 4 + head] = ps;
        ad1[(size_t)node * 4 + head] = pd;
      }
    }
  }
}

// ---- GEMM2 tile: h2[n,64] = x2[n,256] @ W2[256,64] + alpha epilogue ----
__device__ __forceinline__ void gemm2_tile(
    int tile, const float* __restrict__ x2, const float* __restrict__ W2,
    const float* __restrict__ asv, const float* __restrict__ adv,
    float* __restrict__ h2, float* __restrict__ as2, float* __restrict__ ad2,
    int nN, float* smem) {
  float* xs = smem;             // 32*68
  float* Ws = smem + 32 * 68;   // 64*64
  int t = threadIdx.x;
  int nbase = tile * 32;
  int c0 = (t & 15) * 4;
  int n0 = (t >> 4) * 2;
  float acc[2][4];
  for (int i = 0; i < 2; ++i) for (int j = 0; j < 4; ++j) acc[i][j] = 0.f;
  v4 z = (v4)(0.f);
  for (int kc = 0; kc < 4; ++kc) {
    __syncthreads();
    {
      int sn = t >> 3;
      int node = nbase + sn;
      int kp = (t & 7) * 8;
      bool v = node < nN;
      const float* sp = &x2[(size_t)(v ? node : nN - 1) * 256 + kc * 64 + kp];
      v4 a0 = v ? *(const v4*)(sp + 0) : z;
      v4 a1 = v ? *(const v4*)(sp + 4) : z;
      *(v4*)&xs[sn * 68 + kp + 0] = a0;
      *(v4*)&xs[sn * 68 + kp + 4] = a1;
    }
    {
      int kk = t >> 2;
      int cp = (t & 3) * 16;
      const float* wp = &W2[(size_t)(kc * 64 + kk) * 64 + cp];
      v4 w0 = *(const v4*)(wp + 0);
      v4 w1 = *(const v4*)(wp + 4);
      v4 w2 = *(const v4*)(wp + 8);
      v4 w3 = *(const v4*)(wp + 12);
      *(v4*)&Ws[kk * 64 + cp + 0]  = w0;
      *(v4*)&Ws[kk * 64 + cp + 4]  = w1;
      *(v4*)&Ws[kk * 64 + cp + 8]  = w2;
      *(v4*)&Ws[kk * 64 + cp + 12] = w3;
    }
    __syncthreads();
    #pragma unroll 4
    for (int kk = 0; kk < 64; kk += 4) {
      v4 xv[2], wv[4];
      for (int i = 0; i < 2; ++i) xv[i] = *(const v4*)&xs[(n0 + i) * 68 + kk];
      for (int j = 0; j < 4; ++j) wv[j] = *(const v4*)&Ws[(kk + j) * 64 + c0];
      for (int i = 0; i < 2; ++i)
        for (int j = 0; j < 4; ++j) {
          float xd = xv[i][j];
          acc[i][0] += xd * wv[j][0];
          acc[i][1] += xd * wv[j][1];
          acc[i][2] += xd * wv[j][2];
          acc[i][3] += xd * wv[j][3];
        }
    }
  }
  v4 asl = *(const v4*)&asv[c0];
  v4 adl = *(const v4*)&adv[c0];
  for (int i = 0; i < 2; ++i) {
    int node = nbase + n0 + i;
    v4 o; o[0] = acc[i][0]; o[1] = acc[i][1]; o[2] = acc[i][2]; o[3] = acc[i][3];
    float ps = o[0]*asl[0] + o[1]*asl[1] + o[2]*asl[2] + o[3]*asl[3];
    float pd = o[0]*adl[0] + o[1]*adl[1] + o[2]*adl[2] + o[3]*adl[3];
    ps += __shfl_xor(ps, 1); pd += __shfl_xor(pd, 1);
    ps += __shfl_xor(ps, 2); pd += __shfl_xor(pd, 2);
    ps += __shfl_xor(ps, 4); pd += __shfl_xor(pd, 4);
    ps += __shfl_xor(ps, 8); pd += __shfl_xor(pd, 8);
    if (node < nN) {
      *(v4*)&h2[(size_t)node * 64 + c0] = o;
      if ((t & 15) == 0) { as2[node] = ps; ad2[node] = pd; }
    }
  }
}

// ---- the persistent mega-kernel: all phases, software grid barriers ----
__global__ __launch_bounds__(256, 4) void k_mega(
    const int* __restrict__ nidx, const int* __restrict__ ei,
    const float* __restrict__ emb,
    const float* __restrict__ W1, const float* __restrict__ as1v,
    const float* __restrict__ ad1v, const float* __restrict__ b1,
    const float* __restrict__ W2, const float* __restrict__ as2v,
    const float* __restrict__ ad2v, const float* __restrict__ b2,
    const float* __restrict__ gW1, const float* __restrict__ gb1,
    const float* __restrict__ gW2, const float* __restrict__ gb2,
    float* __restrict__ h1, float* __restrict__ x2, float* __restrict__ h2,
    float* __restrict__ as1, float* __restrict__ ad1,
    float* __restrict__ as2, float* __restrict__ ad2,
    int* __restrict__ rowptr, int* __restrict__ cursor, int* __restrict__ srt,
    int* __restrict__ deg, float* __restrict__ pnum, float* __restrict__ pden,
    int* __restrict__ bar, int* __restrict__ bsum,
    float* __restrict__ out, int nN, int nE, int eT) {
  __shared__ __align__(16) float smem[SMEM_FLOATS];
  const int b = blockIdx.x, t = threadIdx.x, nblk = gridDim.x;
  const int wv = t >> 6, lane = t & 63;

  // ---- P0: degree histogram ----
  for (int e = b * 256 + t; e < eT; e += nblk * 256) {
    int d = (e < nE) ? ei[nE + e] : (e - nE);
    atomicAdd(&deg[d], 1);
  }
  gsync(bar, 1, nblk);

  // ---- P1: per-block chunk sums of deg ----
  const int chunk = (nN + nblk - 1) / nblk;
  int beg = b * chunk; if (beg > nN) beg = nN;
  int end = beg + chunk; if (end > nN) end = nN;
  {
    int part = 0;
    for (int i = beg + t; i < end; i += 256) part += deg[i];
    int* red = (int*)smem;
    red[t] = part; __syncthreads();
    for (int off = 128; off; off >>= 1) { if (t < off) red[t] += red[t + off]; __syncthreads(); }
    if (t == 0) bsum[b] = red[0];
  }
  gsync(bar, 2, nblk);

  // ---- P2: each block computes its prefix offset + writes rowptr/cursor ----
  {
    int part = 0;
    for (int j = t; j < b; j += 256) part += bsum[j];
    int* red = (int*)smem;
    red[t] = part; __syncthreads();
    for (int off = 128; off; off >>= 1) { if (t < off) red[t] += red[t + off]; __syncthreads(); }
    int boff = red[0];
    __syncthreads();
    if (wv == 0) {               // wave 0 scans the chunk in 64-wide steps
      int carry = 0;
      for (int base0 = beg; base0 < end; base0 += 64) {
        int idx = base0 + lane;
        int d = (idx < end) ? deg[idx] : 0;
        int sc = d;
        for (int off = 1; off < 64; off <<= 1) {
          int v = __shfl_up(sc, off);
          if (lane >= off) sc += v;
        }
        if (idx < end) { int v = boff + carry + sc - d; rowptr[idx] = v; cursor[idx] = v; }
        carry += __shfl(sc, 63);
      }
    }
    if (b == 0 && t == 0) rowptr[nN] = eT;
  }
  gsync(bar, 3, nblk);

  // ---- P3: scatter edges (dst-sorted) + gemm1 tiles ----
  for (int e = b * 256 + t; e < eT; e += nblk * 256) {
    int s, d;
    if (e < nE) { s = ei[e]; d = ei[nE + e]; } else { s = d = e - nE; }
    int pos = atomicAdd(&cursor[d], 1);
    srt[pos] = s;
  }
  {
    int ntile = ((nN + 63) >> 6) * 4;
    for (int tile = b; tile < ntile; tile += nblk)
      gemm1_tile(tile, nidx, emb, W1, as1v, ad1v, h1, as1, ad1, nN, smem);
  }
  gsync(bar, 4, nblk);

  // ---- P4: layer-1 softmax + aggregate + bias + ELU (one wave per node) ----
  {
    int*   ss = (int*)smem;       // [4][64]
    float* sw = smem + 256;       // [4][256]
    int*   ssw = ss + wv * 64;
    float* sww = sw + wv * 256;
    for (int n = b * 4 + wv; n < nN; n += nblk * 4) {
      int ms0 = rowptr[n], ms1 = rowptr[n + 1];
      v4 adn = *(const v4*)&ad1[(size_t)n * 4];
      int h = lane >> 4;
      v4 acc = (v4)(0.f);
      float den = 0.f;
      for (int base0 = ms0; base0 < ms1; base0 += 64) {
        int m = ms1 - base0; if (m > 64) m = 64;
        WAITLDS();
        if (lane < m) {
          int s = srt[base0 + lane];
          ssw[lane] = s;
          v4 a = *(const v4*)&as1[(size_t)s * 4];
          sww[lane * 4 + 0] = __expf(leaky(a[0] + adn[0]));
          sww[lane * 4 + 1] = __expf(leaky(a[1] + adn[1]));
          sww[lane * 4 + 2] = __expf(leaky(a[2] + adn[2]));
          sww[lane * 4 + 3] = __expf(leaky(a[3] + adn[3]));
        }
        WAITLDS();
        #pragma unroll 8
        for (int j = 0; j < m; ++j) {
          int s = ssw[j];
          float wj = sww[j * 4 + h];
          v4 hv = *(const v4*)&h1[(size_t)s * 256 + lane * 4];
          acc[0] += wj * hv[0];
          acc[1] += wj * hv[1];
          acc[2] += wj * hv[2];
          acc[3] += wj * hv[3];
          den += wj;
        }
      }
      v4 bb = *(const v4*)&b1[lane * 4];
      float inv = 1.f / den;
      v4 o;
      o[0] = elu(acc[0] * inv + bb[0]);
      o[1] = elu(acc[1] * inv + bb[1]);
      o[2] = elu(acc[2] * inv + bb[2]);
      o[3] = elu(acc[3] * inv + bb[3]);
      *(v4*)&x2[(size_t)n * 256 + lane * 4] = o;
    }
  }
  gsync(bar, 5, nblk);

  // ---- P5: gemm2 tiles ----
  {
    int ntile2 = (nN + 31) >> 5;
    for (int tile = b; tile < ntile2; tile += nblk)
      gemm2_tile(tile, x2, W2, as2v, ad2v, h2, as2, ad2, nN, smem);
  }
  gsync(bar, 6, nblk);

  // ---- P6: fused layer-2 aggregate + ELU + gate MLP + pooled partials ----
  {
    float* gwT  = smem;                     // 64*68 = 4352
    int*   ssT  = (int*)(smem + 4352);      // [4][64]
    float* swT  = smem + 4352 + 256;        // [4][64]
    float* xrT  = smem + 4352 + 512;        // [4][64]
    float* snum = smem + 4352 + 768;        // [4][64]
    float* sden = smem + 4352 + 1024;       // [4]
    for (int i = t; i < 4096; i += 256) {
      int d = i >> 6, c = i & 63;
      gwT[c * 68 + d] = gW1[i];
    }
    float gb1l = gb1[lane], gw2l = gW2[lane], gb2s = gb2[0], b2l = b2[lane];
    __syncthreads();
    int*   ssw = ssT + wv * 64;
    float* sww = swT + wv * 64;
    float* xrw = xrT + wv * 64;
    float num = 0.f, denp = 0.f;
    for (int n = b * 4 + wv; n < nN; n += nblk * 4) {
      int ms0 = rowptr[n], ms1 = rowptr[n + 1];
      float adn = ad2[n];
      float acc = 0.f, den = 0.f;
      for (int base0 = ms0; base0 < ms1; base0 += 64) {
        int m = ms1 - base0; if (m > 64) m = 64;
        WAITLDS();
        if (lane < m) {
          int s = srt[base0 + lane];
          ssw[lane] = s;
          sww[lane] = __expf(leaky(as2[s] + adn));
        }
        WAITLDS();
        #pragma unroll 8
        for (int j = 0; j < m; ++j) {
          int s = ssw[j];
          float wj = sww[j];
          acc += wj * h2[(size_t)s * 64 + lane];
          den += wj;
        }
      }
      float x3v = elu(acc / den + b2l);
      WAITLDS();
      xrw[lane] = x3v;
      WAITLDS();
      float hid = gb1l;
      for (int d4 = 0; d4 < 64; d4 += 4) {
        v4 xs4 = *(const v4*)&xrw[d4];
        v4 gv  = *(const v4*)&gwT[lane * 68 + d4];
        hid += xs4[0] * gv[0] + xs4[1] * gv[1] + xs4[2] * gv[2] + xs4[3] * gv[3];
      }
      hid = fmaxf(hid, 0.f);
      float p = hid * gw2l;
      for (int o = 32; o; o >>= 1) p += __shfl_xor(p, o);
      float g = __expf(p + gb2s);
      num += g * x3v;
      denp += g;
    }
    snum[wv * 64 + lane] = num;
    if (lane == 0) sden[wv] = denp;
    __syncthreads();
    if (t < 64) atomicAdd(&pnum[t], snum[t] + snum[64 + t] + snum[128 + t] + snum[192 + t]);
    if (t == 0) atomicAdd(pden, sden[0] + sden[1] + sden[2] + sden[3]);
  }
  gsync(bar, 7, nblk);

  // ---- P7: final output (block 0) ----
  if (b == 0 && t < 64) {
    float nv = atomicAdd(&pnum[t], 0.f);   // coherent device-scope read
    float dv = atomicAdd(pden, 0.f);
    out[t] = nv / dv;
  }
}

extern "C" void kernel_launch(void* const* d_in, const int* in_sizes, int n_in,
                              void* d_out, int out_size, void* d_ws, size_t ws_size,
                              hipStream_t stream) {
  const int*   nidx = (const int*)d_in[0];
  const int*   ei   = (const int*)d_in[1];
  const float* emb  = (const float*)d_in[2];
  const float* W1   = (const float*)d_in[3];
  const float* as1v = (const float*)d_in[4];
  const float* ad1v = (const float*)d_in[5];
  const float* b1   = (const float*)d_in[6];
  const float* W2   = (const float*)d_in[7];
  const float* as2v = (const float*)d_in[8];
  const float* ad2v = (const float*)d_in[9];
  const float* b2   = (const float*)d_in[10];
  const float* gW1  = (const float*)d_in[11];
  const float* gb1  = (const float*)d_in[12];
  const float* gW2  = (const float*)d_in[13];
  const float* gb2  = (const float*)d_in[14];
  float* out = (float*)d_out;

  const int nN = in_sizes[0];
  const int nE = in_sizes[1] / 2;
  const int eT = nE + nN;

  float* f = (float*)d_ws;
  size_t off = 0;
  float* h1   = f + off; off += (size_t)nN * 256;
  float* x2   = f + off; off += (size_t)nN * 256;
  float* as1  = f + off; off += (size_t)nN * 4;
  float* ad1  = f + off; off += (size_t)nN * 4;
  float* as2  = f + off; off += nN;
  float* ad2  = f + off; off += nN;
  int* rowptr = (int*)(f + off); off += nN + 1;
  int* cursor = (int*)(f + off); off += nN;
  int* srt    = (int*)(f + off); off += eT;
  // zeroed region: [deg | pnum | pden | bar]  (nN + 66 ints)
  int*   deg  = (int*)(f + off); off += nN;
  float* pnum = f + off; off += 64;
  float* pden = f + off; off += 1;
  int*   bar  = (int*)(f + off); off += 1;
  int*   bsum = (int*)(f + off); off += 4096;
  // dedicated h2 (avoids aliasing h1's cached lines) when workspace allows
  float* h2 = h1;
  if ((off + (size_t)nN * 64) * sizeof(float) <= ws_size) {
    h2 = f + off; off += (size_t)nN * 64;
  }

  hipMemsetAsync(deg, 0, (size_t)(nN + 66) * sizeof(int), stream);

  // grid sized for guaranteed co-residency (software grid barrier requirement)
  int dev = 0; hipGetDevice(&dev);
  int numCU = 256;
  hipDeviceGetAttribute(&numCU, hipDeviceAttributeMultiprocessorCount, dev);
  int bpc = 0;
  hipOccupancyMaxActiveBlocksPerMultiprocessor(&bpc, (const void*)k_mega, 256, 0);
  if (bpc < 1) bpc = 1;
  if (bpc > 4) bpc = 4;
  int grid = numCU * bpc;
  if (grid > 4096) grid = 4096;   // bsum capacity

  k_mega<<<grid, 256, 0, stream>>>(nidx, ei, emb,
                                   W1, as1v, ad1v, b1,
                                   W2, as2v, ad2v, b2,
                                   gW1, gb1, gW2, gb2,
                                   h1, x2, h2, as1, ad1, as2, ad2,
                                   rowptr, cursor, srt, deg, pnum, pden,
                                   bar, bsum, out, nN, nE, eT);
}